// Round 12
// baseline (468.756 us; speedup 1.0000x reference)
//
#include <hip/hip_runtime.h>

// ---------------------------------------------------------------------------
// DNANet round 12: wave-per-node attention (round 11, unchanged for L=2/3),
// dedicated 8-edges/iter sum kernel for L=1, ILP-4 projections.
// N=50000, E=600000 (+N self loops), HID=64, HEADS=4, d=16.
//
// PL[node][l][dim] u32 = bf16(k_l) | bf16(v_l * dinv[node])<<16  (768 B/node)
// V0[node][dim]    u16 = bf16(v_0 * dinv[node])                  (128 B/node)
// q pre-scaled by 1/sqrt(d)=0.25.
// ---------------------------------------------------------------------------

__device__ inline unsigned short bf16_rne(float f) {
    unsigned int u = __float_as_uint(f);
    unsigned int r = u + 0x7FFFu + ((u >> 16) & 1u);
    return (unsigned short)(r >> 16);
}
__device__ inline float kf(unsigned int u) { return __uint_as_float(u << 16); }
__device__ inline float vf(unsigned int u) { return __uint_as_float(u & 0xFFFF0000u); }

__global__ __launch_bounds__(256) void hist_dst_k(const int* __restrict__ dst,
                                                  int* __restrict__ cnt, int E) {
    int e = blockIdx.x * 256 + threadIdx.x;
    if (e < E) atomicAdd(&cnt[dst[e]], 1);
}

// Exclusive scan of (cnt[i]+1), stage 1 (1024-elem chunks); also emits dinv.
__global__ __launch_bounds__(256) void scan1_k(const int* __restrict__ cnt,
                                               int* __restrict__ excl,
                                               int* __restrict__ aux,
                                               float* __restrict__ dinv, int N) {
    __shared__ int wtot[4];
    int b = blockIdx.x, t = threadIdx.x;
    int lane = t & 63, w = t >> 6;
    int base = b * 1024 + t * 4;
    int v0 = (base + 0 < N) ? cnt[base + 0] + 1 : 0;
    int v1 = (base + 1 < N) ? cnt[base + 1] + 1 : 0;
    int v2 = (base + 2 < N) ? cnt[base + 2] + 1 : 0;
    int v3 = (base + 3 < N) ? cnt[base + 3] + 1 : 0;
    if (base + 0 < N) dinv[base + 0] = rsqrtf((float)v0);
    if (base + 1 < N) dinv[base + 1] = rsqrtf((float)v1);
    if (base + 2 < N) dinv[base + 2] = rsqrtf((float)v2);
    if (base + 3 < N) dinv[base + 3] = rsqrtf((float)v3);
    int s = v0 + v1 + v2 + v3;
    int incl = s;
#pragma unroll
    for (int off = 1; off < 64; off <<= 1) {
        int u = __shfl_up(incl, off);
        if (lane >= off) incl += u;
    }
    if (lane == 63) wtot[w] = incl;
    __syncthreads();
    int wb = 0;
#pragma unroll
    for (int j = 0; j < 4; ++j) if (j < w) wb += wtot[j];
    int ex = wb + incl - s;
    if (base + 0 < N) excl[base + 0] = ex;
    if (base + 1 < N) excl[base + 1] = ex + v0;
    if (base + 2 < N) excl[base + 2] = ex + v0 + v1;
    if (base + 3 < N) excl[base + 3] = ex + v0 + v1 + v2;
    if (t == 0) aux[b] = wtot[0] + wtot[1] + wtot[2] + wtot[3];
}

// Add chunk bases (wave-reduce over aux), mirror into cursor, write offs[N].
__global__ __launch_bounds__(256) void scan_add2_k(int* __restrict__ offs,
                                                   const int* __restrict__ aux,
                                                   const int* __restrict__ cnt,
                                                   int* __restrict__ cursor,
                                                   int N, int nb) {
    int i = blockIdx.x * 256 + threadIdx.x;
    int c = blockIdx.x >> 2;                  // 1024-chunk id
    int lane = threadIdx.x & 63;
    int v = (lane < c && lane < nb) ? aux[lane] : 0;
#pragma unroll
    for (int off = 32; off >= 1; off >>= 1) v += __shfl_xor(v, off);
    if (i < N) {
        int o = offs[i] + v;
        offs[i] = o;
        cursor[i] = o;
        if (i == N - 1) offs[N] = o + cnt[i] + 1;
    }
}

__global__ __launch_bounds__(256) void scatter_dst_k(const int* __restrict__ src,
                                                     const int* __restrict__ dst,
                                                     int* __restrict__ cursor,
                                                     int* __restrict__ src_sorted,
                                                     int E, int N) {
    int e = blockIdx.x * 256 + threadIdx.x;
    int M = E + N;
    if (e >= M) return;
    int s, d;
    if (e < E) { s = src[e]; d = dst[e]; }
    else       { s = d = e - E; }
    int pos = atomicAdd(&cursor[d], 1);
    src_sorted[pos] = s;
}

// h[N x 64] = x[N x 128] @ W[128 x 64] + b ; 16 rows/block (4 rows/thread).
__global__ __launch_bounds__(256) void lin128_64_k(const float* __restrict__ x,
                                                   const float* __restrict__ W,
                                                   const float* __restrict__ b,
                                                   float* __restrict__ y, int N) {
    __shared__ float sW[128 * 64];
    __shared__ float sb[64];
    for (int i = threadIdx.x; i < 128 * 64; i += 256) sW[i] = W[i];
    if (threadIdx.x < 64) sb[threadIdx.x] = b[threadIdx.x];
    __syncthreads();
    int w = threadIdx.x >> 6, c = threadIdx.x & 63;
    int r0 = blockIdx.x * 16 + w * 4;
    if (r0 >= N) return;
    const float* xr[4];
#pragma unroll
    for (int j = 0; j < 4; ++j) {
        int r = r0 + j; if (r > N - 1) r = N - 1;
        xr[j] = x + (size_t)r * 128;
    }
    float acc[4];
#pragma unroll
    for (int j = 0; j < 4; ++j) acc[j] = sb[c];
    for (int k = 0; k < 128; ++k) {
        float wv = sW[k * 64 + c];
#pragma unroll
        for (int j = 0; j < 4; ++j) acc[j] = fmaf(xr[j][k], wv, acc[j]);
    }
#pragma unroll
    for (int j = 0; j < 4; ++j) {
        int r = r0 + j;
        if (r < N) y[(size_t)r * 64 + c] = acc[j];
    }
}

// Projection: X (N x 64 fp32) -> q (x0.25), PL chunk l (bf16 k|v), V0 opt.
// Block = 192 threads = 3 waves (roles Q,K,V); lane holds W[:,c] in VGPRs;
// rows broadcast via readlane, 4 rows in flight (independent FMA chains).
template <bool WRITE_V0>
__global__ __launch_bounds__(192) void proj_qkv_k(const float* __restrict__ X,
                                                  const float* __restrict__ Wq, const float* __restrict__ bq,
                                                  const float* __restrict__ Wk, const float* __restrict__ bk,
                                                  const float* __restrict__ Wv, const float* __restrict__ bv,
                                                  const float* __restrict__ dinv,
                                                  float* __restrict__ q,
                                                  unsigned int* __restrict__ PL,
                                                  unsigned short* __restrict__ V0,
                                                  int N, int l, int RPB) {
    int w = threadIdx.x >> 6;    // role: 0=Q 1=K 2=V
    int c = threadIdx.x & 63;
    const float* W = (w == 0) ? Wq : (w == 1) ? Wk : Wv;
    const float* B = (w == 0) ? bq : (w == 1) ? bk : bv;
    float wr[64];
#pragma unroll
    for (int k = 0; k < 64; ++k) wr[k] = W[k * 64 + c];
    float bias = B[c];
    int r0 = blockIdx.x * RPB;
    int r1 = r0 + RPB; if (r1 > N) r1 = N;
    unsigned short* PLh = (unsigned short*)PL;
    for (int r = r0; r < r1; r += 4) {
        int ra = r;
        int rb = r + 1 < r1 ? r + 1 : r1 - 1;
        int rc = r + 2 < r1 ? r + 2 : r1 - 1;
        int rd = r + 3 < r1 ? r + 3 : r1 - 1;
        float x0 = X[(size_t)ra * 64 + c];
        float x1 = X[(size_t)rb * 64 + c];
        float x2 = X[(size_t)rc * 64 + c];
        float x3 = X[(size_t)rd * 64 + c];
        float a0 = bias, a1 = bias, a2 = bias, a3 = bias;
#pragma unroll
        for (int k = 0; k < 64; ++k) {
            float wk = wr[k];
            a0 = fmaf(__int_as_float(__builtin_amdgcn_readlane(__float_as_int(x0), k)), wk, a0);
            a1 = fmaf(__int_as_float(__builtin_amdgcn_readlane(__float_as_int(x1), k)), wk, a1);
            a2 = fmaf(__int_as_float(__builtin_amdgcn_readlane(__float_as_int(x2), k)), wk, a2);
            a3 = fmaf(__int_as_float(__builtin_amdgcn_readlane(__float_as_int(x3), k)), wk, a3);
        }
        float av[4] = {a0, a1, a2, a3};
#pragma unroll
        for (int j = 0; j < 4; ++j) {
            int rr = r + j;
            if (rr >= r1) break;
            float a = av[j];
            if (w == 0) {
                q[(size_t)rr * 64 + c] = a * 0.25f;      // fold 1/sqrt(16)
            } else if (w == 1) {
                PLh[((size_t)rr * 192 + l * 64 + c) * 2] = bf16_rne(a);
            } else {
                unsigned short vb = bf16_rne(a * dinv[rr]);
                PLh[((size_t)rr * 192 + l * 64 + c) * 2 + 1] = vb;
                if (WRITE_V0) V0[(size_t)rr * 64 + c] = vb;
            }
        }
    }
}

// Layer-1 attention degenerates to a neighbor sum of v0*dinv.
// One dst node per wave; 8-lane groups x uint4 loads = 8 edges/iteration,
// depth-2 prefetch; cross-group shfl combine; no atomics.
__global__ __launch_bounds__(256) void attn_sum_k(const int* __restrict__ offs,
                                                  const int* __restrict__ src_sorted,
                                                  const float* __restrict__ dinv,
                                                  const unsigned short* __restrict__ V0,
                                                  float* __restrict__ out, int N) {
    int wv   = threadIdx.x >> 6;
    int lane = threadIdx.x & 63;
    int og   = lane >> 3;                 // edge-group 0..7
    int ol   = lane & 7;                  // dim-oct (8 dims per lane)
    int d    = blockIdx.x * 4 + wv;
    if (d >= N) return;

    float b0 = 0.f, b1 = 0.f, b2 = 0.f, b3 = 0.f;
    float b4 = 0.f, b5 = 0.f, b6 = 0.f, b7 = 0.f;
    int beg = offs[d], end = offs[d + 1];

    for (int base = beg; base < end; base += 64) {
        int m = end - base;
        if (m > 64) m = 64;
        int sid = (base + lane < end) ? src_sorted[base + lane] : 0;
        int mm1 = m - 1;
        int nit = (m + 7) >> 3;

        int idx = og; if (idx > mm1) idx = mm1;
        int sA = __shfl(sid, idx);
        uint4 A = *(const uint4*)(V0 + (size_t)sA * 64 + ol * 8);

        for (int i = 0; i < nit; ++i) {
            int nidx = (i + 1) * 8 + og; if (nidx > mm1) nidx = mm1;
            int sB = __shfl(sid, nidx);
            uint4 B = *(const uint4*)(V0 + (size_t)sB * 64 + ol * 8);

            float vm = ((i * 8 + og) <= mm1) ? 1.f : 0.f;
            b0 = fmaf(vm, kf(A.x), b0);
            b1 = fmaf(vm, vf(A.x), b1);
            b2 = fmaf(vm, kf(A.y), b2);
            b3 = fmaf(vm, vf(A.y), b3);
            b4 = fmaf(vm, kf(A.z), b4);
            b5 = fmaf(vm, vf(A.z), b5);
            b6 = fmaf(vm, kf(A.w), b6);
            b7 = fmaf(vm, vf(A.w), b7);
            A = B;
        }
    }

#pragma unroll
    for (int off = 8; off <= 32; off <<= 1) {
        b0 += __shfl_xor(b0, off);
        b1 += __shfl_xor(b1, off);
        b2 += __shfl_xor(b2, off);
        b3 += __shfl_xor(b3, off);
        b4 += __shfl_xor(b4, off);
        b5 += __shfl_xor(b5, off);
        b6 += __shfl_xor(b6, off);
        b7 += __shfl_xor(b7, off);
    }
    if (og == 0) {
        float dv = dinv[d];
        float* op = out + (size_t)d * 64 + ol * 8;
        *(float4*)(op + 0) = make_float4(b0 * dv, b1 * dv, b2 * dv, b3 * dv);
        *(float4*)(op + 4) = make_float4(b4 * dv, b5 * dv, b6 * dv, b7 * dv);
    }
}

// Wave-per-node attention: 4 edges/iteration, depth-2 prefetch, no divergence.
// EMIT_OUT: fused W_out epilogue (4 nodes/block).
template <int L, bool EMIT_OUT>
__global__ __launch_bounds__(256) void attn_w64_k(const int* __restrict__ offs,
                                                  const int* __restrict__ src_sorted,
                                                  const float* __restrict__ dinv,
                                                  const float* __restrict__ q,
                                                  const unsigned int* __restrict__ PL,
                                                  const float* __restrict__ Wo,
                                                  const float* __restrict__ bo,
                                                  float* __restrict__ outv,   // rows (Nx64) or final (Nx16)
                                                  int N) {
    constexpr int LDSN = EMIT_OUT ? (4 * 68 + 64 * 16 + 16) : 1;
    __shared__ float lds[LDSN];
    float* rowS = lds;                    // [4][68]
    float* sWo  = lds + 4 * 68;           // [64][16]
    float* sbo  = sWo + 64 * 16;          // [16]
    if (EMIT_OUT) {
        for (int i = threadIdx.x; i < 64 * 16; i += 256) sWo[i] = Wo[i];
        if (threadIdx.x < 16) sbo[threadIdx.x] = bo[threadIdx.x];
    }

    int wv   = threadIdx.x >> 6;          // wave id in block (node slot)
    int lane = threadIdx.x & 63;
    int gl   = lane & 15;                 // dim-quad
    int eg   = lane >> 4;                 // edge-group 0..3
    int d    = blockIdx.x * 4 + wv;

    float a0 = 0.f, a1 = 0.f, a2 = 0.f, a3 = 0.f;

    if (d < N) {
        int beg = offs[d], end = offs[d + 1];
        float4 qv = *(const float4*)(q + (size_t)d * 64 + gl * 4);

        for (int base = beg; base < end; base += 64) {
            int m = end - base;
            if (m > 64) m = 64;
            int sid = (base + lane < end) ? src_sorted[base + lane] : 0;
            int nit = (m + 3) >> 2;
            int mm1 = m - 1;

            int idx = eg; if (idx > mm1) idx = mm1;
            int sA = __shfl(sid, idx);
            uint4 A0, A1, A2, B0, B1, B2;
            {
                const uint4* pa = (const uint4*)(PL + (size_t)sA * 192) + gl;
                A0 = pa[0]; A1 = pa[16]; if (L > 2) A2 = pa[32];
            }

            for (int i = 0; i < nit; ++i) {
                int nidx = (i + 1) * 4 + eg; if (nidx > mm1) nidx = mm1;
                int sB = __shfl(sid, nidx);
                {
                    const uint4* pb = (const uint4*)(PL + (size_t)sB * 192) + gl;
                    B0 = pb[0]; B1 = pb[16]; if (L > 2) B2 = pb[32];
                }

                float vm = ((i * 4 + eg) <= mm1) ? 1.f : 0.f;
                float p0 = qv.x * kf(A0.x);
                p0 = fmaf(qv.y, kf(A0.y), p0);
                p0 = fmaf(qv.z, kf(A0.z), p0);
                p0 = fmaf(qv.w, kf(A0.w), p0);
                float p1 = qv.x * kf(A1.x);
                p1 = fmaf(qv.y, kf(A1.y), p1);
                p1 = fmaf(qv.z, kf(A1.z), p1);
                p1 = fmaf(qv.w, kf(A1.w), p1);
                float p2 = 0.f;
                if (L > 2) {
                    p2 = qv.x * kf(A2.x);
                    p2 = fmaf(qv.y, kf(A2.y), p2);
                    p2 = fmaf(qv.z, kf(A2.z), p2);
                    p2 = fmaf(qv.w, kf(A2.w), p2);
                }
                // head reduce within 4-lane cluster (stays inside group)
                p0 += __shfl_xor(p0, 1); p0 += __shfl_xor(p0, 2);
                p1 += __shfl_xor(p1, 1); p1 += __shfl_xor(p1, 2);
                if (L > 2) { p2 += __shfl_xor(p2, 1); p2 += __shfl_xor(p2, 2); }
                float w0, w1, w2 = 0.f;
                if (L == 2) {
                    float e = __expf(p1 - p0);
                    w0 = __builtin_amdgcn_rcpf(1.0f + e);
                    w1 = 1.0f - w0;
                } else {
                    float mx = fmaxf(fmaxf(p0, p1), p2);
                    float e0 = __expf(p0 - mx);
                    float e1 = __expf(p1 - mx);
                    float e2 = __expf(p2 - mx);
                    float inv = __builtin_amdgcn_rcpf(e0 + e1 + e2);
                    w0 = e0 * inv; w1 = e1 * inv; w2 = e2 * inv;
                }
                w0 *= vm; w1 *= vm; if (L > 2) w2 *= vm;
                a0 = fmaf(w0, vf(A0.x), a0);
                a1 = fmaf(w0, vf(A0.y), a1);
                a2 = fmaf(w0, vf(A0.z), a2);
                a3 = fmaf(w0, vf(A0.w), a3);
                a0 = fmaf(w1, vf(A1.x), a0);
                a1 = fmaf(w1, vf(A1.y), a1);
                a2 = fmaf(w1, vf(A1.z), a2);
                a3 = fmaf(w1, vf(A1.w), a3);
                if (L > 2) {
                    a0 = fmaf(w2, vf(A2.x), a0);
                    a1 = fmaf(w2, vf(A2.y), a1);
                    a2 = fmaf(w2, vf(A2.z), a2);
                    a3 = fmaf(w2, vf(A2.w), a3);
                }
                A0 = B0; A1 = B1;
                if (L > 2) A2 = B2;
            }
        }

        // cross-group combine (4 partial sums -> total in every lane)
        a0 += __shfl_xor(a0, 16); a0 += __shfl_xor(a0, 32);
        a1 += __shfl_xor(a1, 16); a1 += __shfl_xor(a1, 32);
        a2 += __shfl_xor(a2, 16); a2 += __shfl_xor(a2, 32);
        a3 += __shfl_xor(a3, 16); a3 += __shfl_xor(a3, 32);
        float dv = dinv[d];
        a0 *= dv; a1 *= dv; a2 *= dv; a3 *= dv;
    }

    if (EMIT_OUT) {
        if (d < N && eg == 0) {
            rowS[wv * 68 + gl * 4 + 0] = a0;
            rowS[wv * 68 + gl * 4 + 1] = a1;
            rowS[wv * 68 + gl * 4 + 2] = a2;
            rowS[wv * 68 + gl * 4 + 3] = a3;
        }
        __syncthreads();
        if (threadIdx.x < 64) {
            int node = threadIdx.x >> 4;
            int co   = threadIdx.x & 15;
            int dn   = blockIdx.x * 4 + node;
            if (dn < N) {
                float acc = sbo[co];
#pragma unroll 16
                for (int k = 0; k < 64; ++k)
                    acc = fmaf(rowS[node * 68 + k], sWo[k * 16 + co], acc);
                outv[(size_t)dn * 16 + co] = acc;
            }
        }
    } else {
        if (d < N && eg == 0)
            *(float4*)(outv + (size_t)d * 64 + gl * 4) =
                make_float4(a0, a1, a2, a3);
    }
}

extern "C" void kernel_launch(void* const* d_in, const int* in_sizes, int n_in,
                              void* d_out, int out_size, void* d_ws, size_t ws_size,
                              hipStream_t stream) {
    const float* x     = (const float*)d_in[0];
    const int*   ei    = (const int*)d_in[1];
    const float* W_lin = (const float*)d_in[2];
    const float* b_lin = (const float*)d_in[3];
    const float* Wq    = (const float*)d_in[4];
    const float* bq    = (const float*)d_in[5];
    const float* Wk    = (const float*)d_in[6];
    const float* bk    = (const float*)d_in[7];
    const float* Wv    = (const float*)d_in[8];
    const float* bv    = (const float*)d_in[9];
    const float* W_out = (const float*)d_in[10];
    const float* b_out = (const float*)d_in[11];
    float* out = (float*)d_out;

    const int N = in_sizes[0] / 128;
    const int E = in_sizes[1] / 2;
    const int M = E + N;
    const int* srcp = ei;
    const int* dstp = ei + E;

    char* wsb = (char*)d_ws;
    float*          dinv       = (float*)wsb;           wsb += (size_t)N * sizeof(float);
    int*            cnt        = (int*)wsb;             wsb += (size_t)N * sizeof(int);
    int*            offs       = (int*)wsb;             wsb += (size_t)(N + 1) * sizeof(int);
    int*            cursor     = (int*)wsb;             wsb += (size_t)N * sizeof(int);
    int*            aux        = (int*)wsb;             wsb += 64 * sizeof(int);
    int*            src_sorted = (int*)wsb;             wsb += (size_t)M * sizeof(int);
    float*          qb         = (float*)wsb;           wsb += (size_t)N * 64 * sizeof(float);
    unsigned int*   PL         = (unsigned int*)wsb;    wsb += (size_t)N * 192 * sizeof(unsigned int);
    unsigned short* V0p        = (unsigned short*)wsb;  wsb += (size_t)N * 64 * sizeof(unsigned short);
    float*          hA         = (float*)wsb;           wsb += (size_t)N * 64 * sizeof(float);
    float*          outb       = (float*)wsb;

    const int gN   = (N + 255) / 256;
    const int gE   = (E + 255) / 256;
    const int gM   = (M + 255) / 256;
    const int g16  = (N + 15) / 16;
    const int gA4  = (N + 3) / 4;          // attn: 4 nodes (waves) per block
    const int nb   = (N + 1023) / 1024;
    const int RPB  = 16;
    const int gP   = (N + RPB - 1) / RPB;

    // degree -> dinv + dst-CSR
    hipMemsetAsync(cnt, 0, (size_t)N * sizeof(int), stream);
    hist_dst_k<<<gE, 256, 0, stream>>>(dstp, cnt, E);
    scan1_k<<<nb, 256, 0, stream>>>(cnt, offs, aux, dinv, N);
    scan_add2_k<<<gN, 256, 0, stream>>>(offs, aux, cnt, cursor, N, nb);
    scatter_dst_k<<<gM, 256, 0, stream>>>(srcp, dstp, cursor, src_sorted, E, N);

    // slice 0: h = x@W_lin + b -> project/pack chunk 0 (+V0)
    lin128_64_k<<<g16, 256, 0, stream>>>(x, W_lin, b_lin, hA, N);
    proj_qkv_k<true><<<gP, 192, 0, stream>>>(hA, Wq, bq, Wk, bk, Wv, bv, dinv,
                                             qb, PL, V0p, N, 0, RPB);

    // layer 1 (pure neighbor sum of v0)
    attn_sum_k<<<gA4, 256, 0, stream>>>(offs, src_sorted, dinv, V0p, outb, N);
    proj_qkv_k<false><<<gP, 192, 0, stream>>>(outb, Wq, bq, Wk, bk, Wv, bv, dinv,
                                              qb, PL, V0p, N, 1, RPB);
    // layer 2
    attn_w64_k<2, false><<<gA4, 256, 0, stream>>>(offs, src_sorted, dinv, qb, PL,
                                                  nullptr, nullptr, outb, N);
    proj_qkv_k<false><<<gP, 192, 0, stream>>>(outb, Wq, bq, Wk, bk, Wv, bv, dinv,
                                              qb, PL, V0p, N, 2, RPB);
    // layer 3 + fused W_out -> d_out
    attn_w64_k<3, true><<<gA4, 256, 0, stream>>>(offs, src_sorted, dinv, qb, PL,
                                                 W_out, b_out, out, N);
}

// Round 13
// 423.498 us; speedup vs baseline: 1.1069x; 1.1069x over previous
//
#include <hip/hip_runtime.h>

// ---------------------------------------------------------------------------
// DNANet round 13: round-11 pipeline (best measured, 422 us) with ONE change:
// layer 1 uses a dedicated neighbor-sum kernel (8 edges/iter, 128 B/edge).
// N=50000, E=600000 (+N self loops), HID=64, HEADS=4, d=16.
//
// PL[node][l][dim] u32 = bf16(k_l) | bf16(v_l * dinv[node])<<16  (768 B/node)
// V0[node][dim]    u16 = bf16(v_0 * dinv[node])                  (128 B/node)
// q pre-scaled by 1/sqrt(d)=0.25.
//
// attn (L=2,3): one dst node per 64-lane wave; 4 edges/iteration
// (edge-group eg = lane>>4, dim-quad gl = lane&15); depth-2 prefetch;
// cross-group shfl_xor(16,32) combine; fused W_out epilogue on layer 3.
// attn (L=1): pure sum of v0*dinv: 8-lane groups x uint4 = 8 edges/iter.
// ---------------------------------------------------------------------------

__device__ inline unsigned short bf16_rne(float f) {
    unsigned int u = __float_as_uint(f);
    unsigned int r = u + 0x7FFFu + ((u >> 16) & 1u);
    return (unsigned short)(r >> 16);
}
__device__ inline float kf(unsigned int u) { return __uint_as_float(u << 16); }
__device__ inline float vf(unsigned int u) { return __uint_as_float(u & 0xFFFF0000u); }

__global__ __launch_bounds__(256) void hist_dst_k(const int* __restrict__ dst,
                                                  int* __restrict__ cnt, int E) {
    int e = blockIdx.x * 256 + threadIdx.x;
    if (e < E) atomicAdd(&cnt[dst[e]], 1);
}

// Exclusive scan of (cnt[i]+1), stage 1 (1024-elem chunks); also emits dinv.
__global__ __launch_bounds__(256) void scan1_k(const int* __restrict__ cnt,
                                               int* __restrict__ excl,
                                               int* __restrict__ aux,
                                               float* __restrict__ dinv, int N) {
    __shared__ int wtot[4];
    int b = blockIdx.x, t = threadIdx.x;
    int lane = t & 63, w = t >> 6;
    int base = b * 1024 + t * 4;
    int v0 = (base + 0 < N) ? cnt[base + 0] + 1 : 0;
    int v1 = (base + 1 < N) ? cnt[base + 1] + 1 : 0;
    int v2 = (base + 2 < N) ? cnt[base + 2] + 1 : 0;
    int v3 = (base + 3 < N) ? cnt[base + 3] + 1 : 0;
    if (base + 0 < N) dinv[base + 0] = rsqrtf((float)v0);
    if (base + 1 < N) dinv[base + 1] = rsqrtf((float)v1);
    if (base + 2 < N) dinv[base + 2] = rsqrtf((float)v2);
    if (base + 3 < N) dinv[base + 3] = rsqrtf((float)v3);
    int s = v0 + v1 + v2 + v3;
    int incl = s;
#pragma unroll
    for (int off = 1; off < 64; off <<= 1) {
        int u = __shfl_up(incl, off);
        if (lane >= off) incl += u;
    }
    if (lane == 63) wtot[w] = incl;
    __syncthreads();
    int wb = 0;
#pragma unroll
    for (int j = 0; j < 4; ++j) if (j < w) wb += wtot[j];
    int ex = wb + incl - s;
    if (base + 0 < N) excl[base + 0] = ex;
    if (base + 1 < N) excl[base + 1] = ex + v0;
    if (base + 2 < N) excl[base + 2] = ex + v0 + v1;
    if (base + 3 < N) excl[base + 3] = ex + v0 + v1 + v2;
    if (t == 0) aux[b] = wtot[0] + wtot[1] + wtot[2] + wtot[3];
}

// Add chunk bases (wave-reduce over aux), mirror into cursor, write offs[N].
__global__ __launch_bounds__(256) void scan_add2_k(int* __restrict__ offs,
                                                   const int* __restrict__ aux,
                                                   const int* __restrict__ cnt,
                                                   int* __restrict__ cursor,
                                                   int N, int nb) {
    int i = blockIdx.x * 256 + threadIdx.x;
    int c = blockIdx.x >> 2;                  // 1024-chunk id
    int lane = threadIdx.x & 63;
    int v = (lane < c && lane < nb) ? aux[lane] : 0;
#pragma unroll
    for (int off = 32; off >= 1; off >>= 1) v += __shfl_xor(v, off);
    if (i < N) {
        int o = offs[i] + v;
        offs[i] = o;
        cursor[i] = o;
        if (i == N - 1) offs[N] = o + cnt[i] + 1;
    }
}

__global__ __launch_bounds__(256) void scatter_dst_k(const int* __restrict__ src,
                                                     const int* __restrict__ dst,
                                                     int* __restrict__ cursor,
                                                     int* __restrict__ src_sorted,
                                                     int E, int N) {
    int e = blockIdx.x * 256 + threadIdx.x;
    int M = E + N;
    if (e >= M) return;
    int s, d;
    if (e < E) { s = src[e]; d = dst[e]; }
    else       { s = d = e - E; }
    int pos = atomicAdd(&cursor[d], 1);
    src_sorted[pos] = s;
}

// h[N x 64] = x[N x 128] @ W[128 x 64] + b ; 16 rows/block (4 rows/thread).
__global__ __launch_bounds__(256) void lin128_64_k(const float* __restrict__ x,
                                                   const float* __restrict__ W,
                                                   const float* __restrict__ b,
                                                   float* __restrict__ y, int N) {
    __shared__ float sW[128 * 64];
    __shared__ float sb[64];
    for (int i = threadIdx.x; i < 128 * 64; i += 256) sW[i] = W[i];
    if (threadIdx.x < 64) sb[threadIdx.x] = b[threadIdx.x];
    __syncthreads();
    int w = threadIdx.x >> 6, c = threadIdx.x & 63;
    int r0 = blockIdx.x * 16 + w * 4;
    if (r0 >= N) return;
    const float* xr[4];
#pragma unroll
    for (int j = 0; j < 4; ++j) {
        int r = r0 + j; if (r > N - 1) r = N - 1;
        xr[j] = x + (size_t)r * 128;
    }
    float acc[4];
#pragma unroll
    for (int j = 0; j < 4; ++j) acc[j] = sb[c];
    for (int k = 0; k < 128; ++k) {
        float wv = sW[k * 64 + c];
#pragma unroll
        for (int j = 0; j < 4; ++j) acc[j] = fmaf(xr[j][k], wv, acc[j]);
    }
#pragma unroll
    for (int j = 0; j < 4; ++j) {
        int r = r0 + j;
        if (r < N) y[(size_t)r * 64 + c] = acc[j];
    }
}

// Projection: X (N x 64 fp32) -> q (x0.25), PL chunk l (bf16 k|v), V0 opt.
// Block = 192 threads = 3 waves (roles Q,K,V); lane holds W[:,c] in VGPRs;
// row elements broadcast via readlane. RPB rows per block. (round-11 serial)
template <bool WRITE_V0>
__global__ __launch_bounds__(192) void proj_qkv_k(const float* __restrict__ X,
                                                  const float* __restrict__ Wq, const float* __restrict__ bq,
                                                  const float* __restrict__ Wk, const float* __restrict__ bk,
                                                  const float* __restrict__ Wv, const float* __restrict__ bv,
                                                  const float* __restrict__ dinv,
                                                  float* __restrict__ q,
                                                  unsigned int* __restrict__ PL,
                                                  unsigned short* __restrict__ V0,
                                                  int N, int l, int RPB) {
    int w = threadIdx.x >> 6;    // role: 0=Q 1=K 2=V
    int c = threadIdx.x & 63;
    const float* W = (w == 0) ? Wq : (w == 1) ? Wk : Wv;
    const float* B = (w == 0) ? bq : (w == 1) ? bk : bv;
    float wr[64];
#pragma unroll
    for (int k = 0; k < 64; ++k) wr[k] = W[k * 64 + c];
    float bias = B[c];
    int r0 = blockIdx.x * RPB;
    int r1 = r0 + RPB; if (r1 > N) r1 = N;
    unsigned short* PLh = (unsigned short*)PL;
    for (int r = r0; r < r1; ++r) {
        float xv = X[(size_t)r * 64 + c];
        float a = bias;
#pragma unroll
        for (int k = 0; k < 64; ++k) {
            float xk = __int_as_float(__builtin_amdgcn_readlane(__float_as_int(xv), k));
            a = fmaf(xk, wr[k], a);
        }
        if (w == 0) {
            q[(size_t)r * 64 + c] = a * 0.25f;           // fold 1/sqrt(16)
        } else if (w == 1) {
            PLh[((size_t)r * 192 + l * 64 + c) * 2] = bf16_rne(a);
        } else {
            unsigned short vb = bf16_rne(a * dinv[r]);
            PLh[((size_t)r * 192 + l * 64 + c) * 2 + 1] = vb;
            if (WRITE_V0) V0[(size_t)r * 64 + c] = vb;
        }
    }
}

// Layer-1 attention = neighbor sum of v0*dinv.
// One dst node per wave; 8-lane groups x uint4 loads = 8 edges/iteration,
// depth-2 prefetch; cross-group shfl combine; no atomics.
__global__ __launch_bounds__(256) void attn_sum_k(const int* __restrict__ offs,
                                                  const int* __restrict__ src_sorted,
                                                  const float* __restrict__ dinv,
                                                  const unsigned short* __restrict__ V0,
                                                  float* __restrict__ out, int N) {
    int wv   = threadIdx.x >> 6;
    int lane = threadIdx.x & 63;
    int og   = lane >> 3;                 // edge-group 0..7
    int ol   = lane & 7;                  // dim-oct (8 dims per lane)
    int d    = blockIdx.x * 4 + wv;
    if (d >= N) return;

    float b0 = 0.f, b1 = 0.f, b2 = 0.f, b3 = 0.f;
    float b4 = 0.f, b5 = 0.f, b6 = 0.f, b7 = 0.f;
    int beg = offs[d], end = offs[d + 1];

    for (int base = beg; base < end; base += 64) {
        int m = end - base;
        if (m > 64) m = 64;
        int sid = (base + lane < end) ? src_sorted[base + lane] : 0;
        int mm1 = m - 1;
        int nit = (m + 7) >> 3;

        int idx = og; if (idx > mm1) idx = mm1;
        int sA = __shfl(sid, idx);
        uint4 A = *(const uint4*)(V0 + (size_t)sA * 64 + ol * 8);

        for (int i = 0; i < nit; ++i) {
            int nidx = (i + 1) * 8 + og; if (nidx > mm1) nidx = mm1;
            int sB = __shfl(sid, nidx);
            uint4 B = *(const uint4*)(V0 + (size_t)sB * 64 + ol * 8);

            float vm = ((i * 8 + og) <= mm1) ? 1.f : 0.f;
            b0 = fmaf(vm, kf(A.x), b0);
            b1 = fmaf(vm, vf(A.x), b1);
            b2 = fmaf(vm, kf(A.y), b2);
            b3 = fmaf(vm, vf(A.y), b3);
            b4 = fmaf(vm, kf(A.z), b4);
            b5 = fmaf(vm, vf(A.z), b5);
            b6 = fmaf(vm, kf(A.w), b6);
            b7 = fmaf(vm, vf(A.w), b7);
            A = B;
        }
    }

#pragma unroll
    for (int off = 8; off <= 32; off <<= 1) {
        b0 += __shfl_xor(b0, off);
        b1 += __shfl_xor(b1, off);
        b2 += __shfl_xor(b2, off);
        b3 += __shfl_xor(b3, off);
        b4 += __shfl_xor(b4, off);
        b5 += __shfl_xor(b5, off);
        b6 += __shfl_xor(b6, off);
        b7 += __shfl_xor(b7, off);
    }
    if (og == 0) {
        float dv = dinv[d];
        float* op = out + (size_t)d * 64 + ol * 8;
        *(float4*)(op + 0) = make_float4(b0 * dv, b1 * dv, b2 * dv, b3 * dv);
        *(float4*)(op + 4) = make_float4(b4 * dv, b5 * dv, b6 * dv, b7 * dv);
    }
}

// Wave-per-node attention: 4 edges/iteration, depth-2 prefetch, no divergence.
// EMIT_OUT: fused W_out epilogue (4 nodes/block).
template <int L, bool EMIT_OUT>
__global__ __launch_bounds__(256) void attn_w64_k(const int* __restrict__ offs,
                                                  const int* __restrict__ src_sorted,
                                                  const float* __restrict__ dinv,
                                                  const float* __restrict__ q,
                                                  const unsigned int* __restrict__ PL,
                                                  const float* __restrict__ Wo,
                                                  const float* __restrict__ bo,
                                                  float* __restrict__ outv,   // rows (Nx64) or final (Nx16)
                                                  int N) {
    constexpr int LDSN = EMIT_OUT ? (4 * 68 + 64 * 16 + 16) : 1;
    __shared__ float lds[LDSN];
    float* rowS = lds;                    // [4][68]
    float* sWo  = lds + 4 * 68;           // [64][16]
    float* sbo  = sWo + 64 * 16;          // [16]
    if (EMIT_OUT) {
        for (int i = threadIdx.x; i < 64 * 16; i += 256) sWo[i] = Wo[i];
        if (threadIdx.x < 16) sbo[threadIdx.x] = bo[threadIdx.x];
    }

    int wv   = threadIdx.x >> 6;          // wave id in block (node slot)
    int lane = threadIdx.x & 63;
    int gl   = lane & 15;                 // dim-quad
    int eg   = lane >> 4;                 // edge-group 0..3
    int d    = blockIdx.x * 4 + wv;

    float a0 = 0.f, a1 = 0.f, a2 = 0.f, a3 = 0.f;

    if (d < N) {
        int beg = offs[d], end = offs[d + 1];
        float4 qv = *(const float4*)(q + (size_t)d * 64 + gl * 4);

        for (int base = beg; base < end; base += 64) {
            int m = end - base;
            if (m > 64) m = 64;
            int sid = (base + lane < end) ? src_sorted[base + lane] : 0;
            int nit = (m + 3) >> 2;
            int mm1 = m - 1;

            int idx = eg; if (idx > mm1) idx = mm1;
            int sA = __shfl(sid, idx);
            uint4 A0, A1, A2, B0, B1, B2;
            {
                const uint4* pa = (const uint4*)(PL + (size_t)sA * 192) + gl;
                A0 = pa[0]; A1 = pa[16]; if (L > 2) A2 = pa[32];
            }

            for (int i = 0; i < nit; ++i) {
                int nidx = (i + 1) * 4 + eg; if (nidx > mm1) nidx = mm1;
                int sB = __shfl(sid, nidx);
                {
                    const uint4* pb = (const uint4*)(PL + (size_t)sB * 192) + gl;
                    B0 = pb[0]; B1 = pb[16]; if (L > 2) B2 = pb[32];
                }

                float vm = ((i * 4 + eg) <= mm1) ? 1.f : 0.f;
                float p0 = qv.x * kf(A0.x);
                p0 = fmaf(qv.y, kf(A0.y), p0);
                p0 = fmaf(qv.z, kf(A0.z), p0);
                p0 = fmaf(qv.w, kf(A0.w), p0);
                float p1 = qv.x * kf(A1.x);
                p1 = fmaf(qv.y, kf(A1.y), p1);
                p1 = fmaf(qv.z, kf(A1.z), p1);
                p1 = fmaf(qv.w, kf(A1.w), p1);
                float p2 = 0.f;
                if (L > 2) {
                    p2 = qv.x * kf(A2.x);
                    p2 = fmaf(qv.y, kf(A2.y), p2);
                    p2 = fmaf(qv.z, kf(A2.z), p2);
                    p2 = fmaf(qv.w, kf(A2.w), p2);
                }
                // head reduce within 4-lane cluster (stays inside group)
                p0 += __shfl_xor(p0, 1); p0 += __shfl_xor(p0, 2);
                p1 += __shfl_xor(p1, 1); p1 += __shfl_xor(p1, 2);
                if (L > 2) { p2 += __shfl_xor(p2, 1); p2 += __shfl_xor(p2, 2); }
                float w0, w1, w2 = 0.f;
                if (L == 2) {
                    float e = __expf(p1 - p0);
                    w0 = __builtin_amdgcn_rcpf(1.0f + e);
                    w1 = 1.0f - w0;
                } else {
                    float mx = fmaxf(fmaxf(p0, p1), p2);
                    float e0 = __expf(p0 - mx);
                    float e1 = __expf(p1 - mx);
                    float e2 = __expf(p2 - mx);
                    float inv = __builtin_amdgcn_rcpf(e0 + e1 + e2);
                    w0 = e0 * inv; w1 = e1 * inv; w2 = e2 * inv;
                }
                w0 *= vm; w1 *= vm; if (L > 2) w2 *= vm;
                a0 = fmaf(w0, vf(A0.x), a0);
                a1 = fmaf(w0, vf(A0.y), a1);
                a2 = fmaf(w0, vf(A0.z), a2);
                a3 = fmaf(w0, vf(A0.w), a3);
                a0 = fmaf(w1, vf(A1.x), a0);
                a1 = fmaf(w1, vf(A1.y), a1);
                a2 = fmaf(w1, vf(A1.z), a2);
                a3 = fmaf(w1, vf(A1.w), a3);
                if (L > 2) {
                    a0 = fmaf(w2, vf(A2.x), a0);
                    a1 = fmaf(w2, vf(A2.y), a1);
                    a2 = fmaf(w2, vf(A2.z), a2);
                    a3 = fmaf(w2, vf(A2.w), a3);
                }
                A0 = B0; A1 = B1;
                if (L > 2) A2 = B2;
            }
        }

        // cross-group combine (4 partial sums -> total in every lane)
        a0 += __shfl_xor(a0, 16); a0 += __shfl_xor(a0, 32);
        a1 += __shfl_xor(a1, 16); a1 += __shfl_xor(a1, 32);
        a2 += __shfl_xor(a2, 16); a2 += __shfl_xor(a2, 32);
        a3 += __shfl_xor(a3, 16); a3 += __shfl_xor(a3, 32);
        float dv = dinv[d];
        a0 *= dv; a1 *= dv; a2 *= dv; a3 *= dv;
    }

    if (EMIT_OUT) {
        if (d < N && eg == 0) {
            rowS[wv * 68 + gl * 4 + 0] = a0;
            rowS[wv * 68 + gl * 4 + 1] = a1;
            rowS[wv * 68 + gl * 4 + 2] = a2;
            rowS[wv * 68 + gl * 4 + 3] = a3;
        }
        __syncthreads();
        if (threadIdx.x < 64) {
            int node = threadIdx.x >> 4;
            int co   = threadIdx.x & 15;
            int dn   = blockIdx.x * 4 + node;
            if (dn < N) {
                float acc = sbo[co];
#pragma unroll 16
                for (int k = 0; k < 64; ++k)
                    acc = fmaf(rowS[node * 68 + k], sWo[k * 16 + co], acc);
                outv[(size_t)dn * 16 + co] = acc;
            }
        }
    } else {
        if (d < N && eg == 0)
            *(float4*)(outv + (size_t)d * 64 + gl * 4) =
                make_float4(a0, a1, a2, a3);
    }
}

extern "C" void kernel_launch(void* const* d_in, const int* in_sizes, int n_in,
                              void* d_out, int out_size, void* d_ws, size_t ws_size,
                              hipStream_t stream) {
    const float* x     = (const float*)d_in[0];
    const int*   ei    = (const int*)d_in[1];
    const float* W_lin = (const float*)d_in[2];
    const float* b_lin = (const float*)d_in[3];
    const float* Wq    = (const float*)d_in[4];
    const float* bq    = (const float*)d_in[5];
    const float* Wk    = (const float*)d_in[6];
    const float* bk    = (const float*)d_in[7];
    const float* Wv    = (const float*)d_in[8];
    const float* bv    = (const float*)d_in[9];
    const float* W_out = (const float*)d_in[10];
    const float* b_out = (const float*)d_in[11];
    float* out = (float*)d_out;

    const int N = in_sizes[0] / 128;
    const int E = in_sizes[1] / 2;
    const int M = E + N;
    const int* srcp = ei;
    const int* dstp = ei + E;

    char* wsb = (char*)d_ws;
    float*          dinv       = (float*)wsb;           wsb += (size_t)N * sizeof(float);
    int*            cnt        = (int*)wsb;             wsb += (size_t)N * sizeof(int);
    int*            offs       = (int*)wsb;             wsb += (size_t)(N + 1) * sizeof(int);
    int*            cursor     = (int*)wsb;             wsb += (size_t)N * sizeof(int);
    int*            aux        = (int*)wsb;             wsb += 64 * sizeof(int);
    int*            src_sorted = (int*)wsb;             wsb += (size_t)M * sizeof(int);
    float*          qb         = (float*)wsb;           wsb += (size_t)N * 64 * sizeof(float);
    unsigned int*   PL         = (unsigned int*)wsb;    wsb += (size_t)N * 192 * sizeof(unsigned int);
    unsigned short* V0p        = (unsigned short*)wsb;  wsb += (size_t)N * 64 * sizeof(unsigned short);
    float*          hA         = (float*)wsb;           wsb += (size_t)N * 64 * sizeof(float);
    float*          outb       = (float*)wsb;

    const int gN   = (N + 255) / 256;
    const int gE   = (E + 255) / 256;
    const int gM   = (M + 255) / 256;
    const int g16  = (N + 15) / 16;
    const int gA4  = (N + 3) / 4;          // attn: 4 nodes (waves) per block
    const int nb   = (N + 1023) / 1024;
    const int RPB  = 16;
    const int gP   = (N + RPB - 1) / RPB;

    // degree -> dinv + dst-CSR
    hipMemsetAsync(cnt, 0, (size_t)N * sizeof(int), stream);
    hist_dst_k<<<gE, 256, 0, stream>>>(dstp, cnt, E);
    scan1_k<<<nb, 256, 0, stream>>>(cnt, offs, aux, dinv, N);
    scan_add2_k<<<gN, 256, 0, stream>>>(offs, aux, cnt, cursor, N, nb);
    scatter_dst_k<<<gM, 256, 0, stream>>>(srcp, dstp, cursor, src_sorted, E, N);

    // slice 0: h = x@W_lin + b -> project/pack chunk 0 (+V0)
    lin128_64_k<<<g16, 256, 0, stream>>>(x, W_lin, b_lin, hA, N);
    proj_qkv_k<true><<<gP, 192, 0, stream>>>(hA, Wq, bq, Wk, bk, Wv, bv, dinv,
                                             qb, PL, V0p, N, 0, RPB);

    // layer 1 (pure neighbor sum of v0)
    attn_sum_k<<<gA4, 256, 0, stream>>>(offs, src_sorted, dinv, V0p, outb, N);
    proj_qkv_k<false><<<gP, 192, 0, stream>>>(outb, Wq, bq, Wk, bk, Wv, bv, dinv,
                                              qb, PL, V0p, N, 1, RPB);
    // layer 2
    attn_w64_k<2, false><<<gA4, 256, 0, stream>>>(offs, src_sorted, dinv, qb, PL,
                                                  nullptr, nullptr, outb, N);
    proj_qkv_k<false><<<gP, 192, 0, stream>>>(outb, Wq, bq, Wk, bk, Wv, bv, dinv,
                                              qb, PL, V0p, N, 2, RPB);
    // layer 3 + fused W_out -> d_out
    attn_w64_k<3, true><<<gA4, 256, 0, stream>>>(offs, src_sorted, dinv, qb, PL,
                                                 W_out, b_out, out, N);
}